// Round 3
// baseline (6572.939 us; speedup 1.0000x reference)
//
#include <hip/hip_runtime.h>
#include <hip/hip_bf16.h>
#include <math.h>

typedef __hip_bfloat16 bf16;
typedef __attribute__((ext_vector_type(4))) float floatx4;
typedef __attribute__((ext_vector_type(8))) short shortx8;

#define T_TOK 1154
#define C_DIM 768
#define H_HEADS 12
#define NLOC 577
#define SP 1160          // scores pitch (>= 1154)
#define OUT_PER 1769472  // 2*576*1536

static __device__ __forceinline__ float b2f(bf16 v) { return __bfloat162float(v); }
static __device__ __forceinline__ bf16 f2b(float v) { return __float2bfloat16(v); }

// ---------------- init: x (f32) -> f32 residual, camera token splice ----------------
__global__ void k_init(const float* __restrict__ xin, const float* __restrict__ cam,
                       float* __restrict__ xF, int total) {
    int idx = blockIdx.x * 256 + threadIdx.x;
    if (idx >= total) return;
    int t = idx / C_DIM, c = idx - t * C_DIM;
    int s = t / NLOC, n = t - s * NLOC;
    float v = (n == 0) ? cam[s * C_DIM + c] : xin[idx];
    xF[idx] = v;
}

// ---------------- cast f32 residual -> bf16 snapshot ----------------
__global__ void k_cast(const float* __restrict__ src, bf16* __restrict__ dst, int total) {
    int idx = blockIdx.x * 256 + threadIdx.x;
    if (idx < total) dst[idx] = f2b(src[idx]);
}

// ---------------- LayerNorm: f32 residual -> bf16 ----------------
__global__ __launch_bounds__(256) void k_ln(const float* __restrict__ xF,
                                            const float* __restrict__ w, const float* __restrict__ b,
                                            bf16* __restrict__ out) {
    int t = blockIdx.x;
    const float* xr = xF + (size_t)t * C_DIM;
    float s = 0.f, s2 = 0.f;
    for (int c = threadIdx.x; c < C_DIM; c += 256) { float v = xr[c]; s += v; s2 += v * v; }
    __shared__ float red[8];
    for (int o = 32; o; o >>= 1) { s += __shfl_xor(s, o, 64); s2 += __shfl_xor(s2, o, 64); }
    int wv = threadIdx.x >> 6;
    if ((threadIdx.x & 63) == 0) { red[wv] = s; red[4 + wv] = s2; }
    __syncthreads();
    s = red[0] + red[1] + red[2] + red[3];
    s2 = red[4] + red[5] + red[6] + red[7];
    float mean = s * (1.0f / C_DIM);
    float var = s2 * (1.0f / C_DIM) - mean * mean;
    if (var < 0.f) var = 0.f;
    float inv = rsqrtf(var + 1e-6f);
    bf16* orow = out + (size_t)t * C_DIM;
    for (int c = threadIdx.x; c < C_DIM; c += 256) {
        float v = (xr[c] - mean) * inv * w[c] + b[c];
        orow[c] = f2b(v);
    }
}

// ---------------- GEMM: out[M,N] = A[M,K](bf16) x Bt[N,K](f32->bf16)^T ----------------
// mode 1: outB = gelu_exact(acc + bias)         (bf16 out)
// mode 2: xio += gamma * (acc + bias)           (f32 residual in-place)
// mode 3: outB = acc + bias                     (bf16 out)
__global__ __launch_bounds__(256) void k_gemm(
    const bf16* __restrict__ A, const float* __restrict__ Bt,
    const float* __restrict__ bias, const float* __restrict__ gamma,
    bf16* __restrict__ outB, float* __restrict__ xio,
    int M, int N, int K, int mode) {
    __shared__ short At[64 * 40];
    __shared__ short Bs[64 * 40];
    int m0 = blockIdx.x * 64, n0 = blockIdx.y * 64;
    int tid = threadIdx.x;
    int wv = tid >> 6, lane = tid & 63;
    int mt = (wv & 1) * 32, nt = (wv >> 1) * 32;
    floatx4 acc[2][2] = {};
    int r = tid >> 2, c8 = (tid & 3) * 8;
    int arow = m0 + r; if (arow >= M) arow = M - 1;
    const bf16* aptr = A + (size_t)arow * K + c8;
    const float* bptr = Bt + (size_t)(n0 + r) * K + c8;
    short* asl = &At[r * 40 + c8];
    short* bsl = &Bs[r * 40 + c8];
    int lrow = lane & 15, lq = lane >> 4;
    for (int k0 = 0; k0 < K; k0 += 32) {
        *(uint4*)asl = *(const uint4*)(aptr);
        float4 w0 = *(const float4*)(bptr);
        float4 w1 = *(const float4*)(bptr + 4);
        bf16 pk[8];
        pk[0] = f2b(w0.x); pk[1] = f2b(w0.y); pk[2] = f2b(w0.z); pk[3] = f2b(w0.w);
        pk[4] = f2b(w1.x); pk[5] = f2b(w1.y); pk[6] = f2b(w1.z); pk[7] = f2b(w1.w);
        *(shortx8*)bsl = *(shortx8*)pk;
        aptr += 32; bptr += 32;
        __syncthreads();
        shortx8 af0 = *(const shortx8*)&At[(mt + lrow) * 40 + lq * 8];
        shortx8 af1 = *(const shortx8*)&At[(mt + 16 + lrow) * 40 + lq * 8];
        shortx8 bg0 = *(const shortx8*)&Bs[(nt + lrow) * 40 + lq * 8];
        shortx8 bg1 = *(const shortx8*)&Bs[(nt + 16 + lrow) * 40 + lq * 8];
        acc[0][0] = __builtin_amdgcn_mfma_f32_16x16x32_bf16(af0, bg0, acc[0][0], 0, 0, 0);
        acc[0][1] = __builtin_amdgcn_mfma_f32_16x16x32_bf16(af0, bg1, acc[0][1], 0, 0, 0);
        acc[1][0] = __builtin_amdgcn_mfma_f32_16x16x32_bf16(af1, bg0, acc[1][0], 0, 0, 0);
        acc[1][1] = __builtin_amdgcn_mfma_f32_16x16x32_bf16(af1, bg1, acc[1][1], 0, 0, 0);
        __syncthreads();
    }
    int colb = n0 + nt + lrow;
    for (int mi = 0; mi < 2; mi++) {
        for (int ni = 0; ni < 2; ni++) {
            int cc = colb + ni * 16;
            #pragma unroll
            for (int rg = 0; rg < 4; rg++) {
                int rr = m0 + mt + mi * 16 + lq * 4 + rg;
                if (rr < M) {
                    float u = acc[mi][ni][rg] + bias[cc];
                    if (mode == 1) {
                        float g = 0.5f * u * (1.0f + erff(u * 0.70710678118f));
                        outB[(size_t)rr * N + cc] = f2b(g);
                    } else if (mode == 2) {
                        xio[(size_t)rr * N + cc] += gamma[cc] * u;
                    } else {
                        outB[(size_t)rr * N + cc] = f2b(u);
                    }
                }
            }
        }
    }
}

// ---------------- qk prep: RMS norm + RoPE, split to head-major bf16 ----------------
__global__ __launch_bounds__(256) void k_qkprep(
    const bf16* __restrict__ qkv,
    const float* __restrict__ qnw, const float* __restrict__ knw,
    const float* __restrict__ ctab, const float* __restrict__ stab, int posMod,
    bf16* __restrict__ qh, bf16* __restrict__ kh, bf16* __restrict__ vh) {
    int gw = blockIdx.x * 4 + (threadIdx.x >> 6);
    int lane = threadIdx.x & 63;
    if (gw >= T_TOK * H_HEADS) return;
    int t = gw / H_HEADS, h = gw - t * H_HEADS;
    size_t base = (size_t)t * 2304 + h * 64 + lane;
    float q = b2f(qkv[base]), k = b2f(qkv[base + 768]), v = b2f(qkv[base + 1536]);
    float sq = q * q, sk = k * k;
    for (int o = 32; o; o >>= 1) { sq += __shfl_xor(sq, o, 64); sk += __shfl_xor(sk, o, 64); }
    q = q * rsqrtf(sq * (1.0f / 64.0f) + 1e-6f) * qnw[lane];
    k = k * rsqrtf(sk * (1.0f / 64.0f) + 1e-6f) * knw[lane];
    int pos = t % posMod;
    float cv = ctab[pos * 64 + lane];
    float sv = stab[pos * 64 + lane];
    float qp = __shfl_xor(q, 16, 64);
    float kp = __shfl_xor(k, 16, 64);
    float sgn = (lane & 16) ? 1.0f : -1.0f;
    float qo = q * cv + sgn * qp * sv;
    float ko = k * cv + sgn * kp * sv;
    size_t oidx = ((size_t)h * T_TOK + t) * 64 + lane;
    qh[oidx] = f2b(qo);
    kh[oidx] = f2b(ko);
    vh[oidx] = f2b(v);
}

// ---------------- attention: 8 q-rows per block, scores in LDS ----------------
__global__ __launch_bounds__(256) void k_attn(
    const bf16* __restrict__ qh, const bf16* __restrict__ kh, const bf16* __restrict__ vh,
    const float* __restrict__ mask, bf16* __restrict__ out, int nk) {
    __shared__ float sc[8 * SP];
    __shared__ float kt[32 * 68];
    __shared__ float qt[8 * 68];
    int h = blockIdx.y;
    int base = blockIdx.z * nk;
    int q0 = blockIdx.x * 8;
    int tid = threadIdx.x;
    for (int idx = tid; idx < 8 * 64; idx += 256) {
        int qi2 = idx >> 6, d = idx & 63;
        int qr = q0 + qi2;
        float v = 0.0f;
        if (qr < nk) v = b2f(qh[((size_t)h * T_TOK + base + qr) * 64 + d]);
        qt[qi2 * 68 + d] = v;
    }
    __syncthreads();
    int qi = tid >> 5, kk = tid & 31;
    int nkt = (nk + 31) >> 5;
    for (int ktile = 0; ktile < nkt; ktile++) {
        __syncthreads();
        for (int idx = tid; idx < 32 * 64; idx += 256) {
            int kr = idx >> 6, d = idx & 63;
            int gk = ktile * 32 + kr;
            float v = 0.0f;
            if (gk < nk) v = b2f(kh[((size_t)h * T_TOK + base + gk) * 64 + d]);
            kt[kr * 68 + d] = v;
        }
        __syncthreads();
        int gk = ktile * 32 + kk;
        if (gk < nk) {
            float acc = 0.f;
            const float* qr = &qt[qi * 68];
            const float* kr = &kt[kk * 68];
            #pragma unroll
            for (int d = 0; d < 64; d += 4) {
                float4 qv = *(const float4*)&qr[d];
                float4 kv = *(const float4*)&kr[d];
                acc += qv.x * kv.x + qv.y * kv.y + qv.z * kv.z + qv.w * kv.w;
            }
            float bias = (1.0f - mask[base + gk]) * -10000.0f;
            sc[qi * SP + gk] = acc * 0.125f + bias;
        }
    }
    __syncthreads();
    // softmax: 32 lanes own one q row (same half-wave -> width-32 shuffles ok)
    int l = tid & 31;
    float m = -3.0e38f;
    for (int k = l; k < nk; k += 32) m = fmaxf(m, sc[qi * SP + k]);
    for (int o = 16; o; o >>= 1) m = fmaxf(m, __shfl_xor(m, o, 32));
    float ssum = 0.f;
    for (int k = l; k < nk; k += 32) { float e = __expf(sc[qi * SP + k] - m); sc[qi * SP + k] = e; ssum += e; }
    for (int o = 16; o; o >>= 1) ssum += __shfl_xor(ssum, o, 32);
    float inv = 1.0f / ssum;
    // PV: each lane owns dims (2l, 2l+1) of its q row
    int qrow = q0 + qi;
    if (qrow >= nk) return;
    const __hip_bfloat162* v2 = (const __hip_bfloat162*)(vh + ((size_t)h * T_TOK + base) * 64);
    float a0 = 0.f, a1 = 0.f;
    for (int k = 0; k < nk; k++) {
        float p = sc[qi * SP + k];
        __hip_bfloat162 vv = v2[k * 32 + l];
        float2 vf = __bfloat1622float2(vv);
        a0 += p * vf.x; a1 += p * vf.y;
    }
    size_t ob = (size_t)(base + qrow) * C_DIM + h * 64 + l * 2;
    out[ob] = f2b(a0 * inv);
    out[ob + 1] = f2b(a1 * inv);
}

// ---------------- output assembly at OUT layers (f32 out) ----------------
__global__ __launch_bounds__(256) void k_output(
    const float* __restrict__ xF, const bf16* __restrict__ lxB,
    const float* __restrict__ fw, const float* __restrict__ fb, float* __restrict__ dst) {
    int b = blockIdx.x;                 // 0..1151
    int s = b / 576, nn = b - s * 576;
    int t = s * NLOC + nn + 1;          // skip token 0
    const float* xr = xF + (size_t)t * C_DIM;
    float sum = 0.f, s2 = 0.f;
    for (int c = threadIdx.x; c < C_DIM; c += 256) { float v = xr[c]; sum += v; s2 += v * v; }
    __shared__ float red[8];
    for (int o = 32; o; o >>= 1) { sum += __shfl_xor(sum, o, 64); s2 += __shfl_xor(s2, o, 64); }
    if ((threadIdx.x & 63) == 0) { red[threadIdx.x >> 6] = sum; red[4 + (threadIdx.x >> 6)] = s2; }
    __syncthreads();
    sum = red[0] + red[1] + red[2] + red[3];
    s2 = red[4] + red[5] + red[6] + red[7];
    float mean = sum * (1.0f / C_DIM);
    float var = s2 * (1.0f / C_DIM) - mean * mean;
    if (var < 0.f) var = 0.f;
    float inv = rsqrtf(var + 1e-6f);
    float* orow = dst + (size_t)b * 1536;
    const bf16* lr = lxB + (size_t)t * C_DIM;
    for (int c = threadIdx.x; c < C_DIM; c += 256) {
        orow[c] = b2f(lr[c]);
        float v = (xr[c] - mean) * inv * fw[c] + fb[c];
        orow[768 + c] = v;
    }
}

// ---------------- camera tokens (layer 11, no final LN) ----------------
__global__ void k_cam(const float* __restrict__ xF, const bf16* __restrict__ lxB,
                      float* __restrict__ dst) {
    for (int idx = threadIdx.x; idx < 2 * 1536; idx += 256) {
        int s = idx / 1536, c = idx - s * 1536;
        int t = s * NLOC;
        float v = (c < 768) ? b2f(lxB[(size_t)t * 768 + c]) : xF[(size_t)t * 768 + (c - 768)];
        dst[idx] = v;
    }
}

extern "C" void kernel_launch(void* const* d_in, const int* in_sizes, int n_in,
                              void* d_out, int out_size, void* d_ws, size_t ws_size,
                              hipStream_t stream) {
    const float* xin  = (const float*)d_in[0];
    const float* rcl  = (const float*)d_in[1];
    const float* rsl  = (const float*)d_in[2];
    const float* rcg  = (const float*)d_in[3];
    const float* rsg  = (const float*)d_in[4];
    const float* kvl  = (const float*)d_in[5];
    const float* kvg  = (const float*)d_in[6];
    const float* cam  = (const float*)d_in[7];
    const float* qkvw = (const float*)d_in[8];
    const float* qkvb = (const float*)d_in[9];
    const float* qnw  = (const float*)d_in[10];
    const float* knw  = (const float*)d_in[11];
    const float* pw   = (const float*)d_in[12];
    const float* pb   = (const float*)d_in[13];
    const float* ls1  = (const float*)d_in[14];
    const float* ls2  = (const float*)d_in[15];
    const float* n1w  = (const float*)d_in[16];
    const float* n1b  = (const float*)d_in[17];
    const float* n2w  = (const float*)d_in[18];
    const float* n2b  = (const float*)d_in[19];
    const float* f1w  = (const float*)d_in[20];
    const float* f1b  = (const float*)d_in[21];
    const float* f2w  = (const float*)d_in[22];
    const float* f2b_ = (const float*)d_in[23];
    const float* fnw  = (const float*)d_in[24];
    const float* fnb  = (const float*)d_in[25];

    // Workspace (~19.5 MB):
    //   xF   f32 [1154][768]
    //   bufA bf16 union{ qkv[1154][2304], mlp[1154][3072] }
    //   qhb/khb/vhb bf16 [12][1154][64]
    //   hbuf bf16 [1154][768]
    //   lxB  bf16 [1154][768]
    char* ws = (char*)d_ws;
    const size_t TC = (size_t)T_TOK * C_DIM;                 // 886,272
    float* xF  = (float*)ws; ws += TC * 4;
    bf16* bufA = (bf16*)ws;  ws += (size_t)T_TOK * 3072 * 2;
    bf16* qhb  = (bf16*)ws;  ws += TC * 2;
    bf16* khb  = (bf16*)ws;  ws += TC * 2;
    bf16* vhb  = (bf16*)ws;  ws += TC * 2;
    bf16* hbuf = (bf16*)ws;  ws += TC * 2;
    bf16* lxB  = (bf16*)ws;  ws += TC * 2;
    (void)ws_size; (void)n_in; (void)in_sizes; (void)out_size;

    float* out_b = (float*)d_out;

    k_init<<<(int)((TC + 255) / 256), 256, 0, stream>>>(xin, cam, xF, (int)TC);

    int outIdx = 0;
    for (int i = 0; i < 12; i++) {
        bool isGlobal = (i & 1);
        // LN1
        k_ln<<<T_TOK, 256, 0, stream>>>(xF, n1w + (size_t)i * 768, n1b + (size_t)i * 768, hbuf);
        // QKV gemm -> bf16 (bufA)
        k_gemm<<<dim3(19, 36), 256, 0, stream>>>(hbuf, qkvw + (size_t)i * 2304 * 768,
            qkvb + (size_t)i * 2304, nullptr, bufA, nullptr, T_TOK, 2304, 768, 3);
        // rms + rope + head split
        k_qkprep<<<(T_TOK * H_HEADS) / 4, 256, 0, stream>>>(bufA,
            qnw + (size_t)i * 64, knw + (size_t)i * 64,
            isGlobal ? rcg : rcl, isGlobal ? rsg : rsl, isGlobal ? 1154 : 577,
            qhb, khb, vhb);
        // attention -> hbuf
        if (isGlobal)
            k_attn<<<dim3(145, 12, 1), 256, 0, stream>>>(qhb, khb, vhb, kvg, hbuf, 1154);
        else
            k_attn<<<dim3(73, 12, 2), 256, 0, stream>>>(qhb, khb, vhb, kvl, hbuf, 577);
        // proj + residual (x += ls1*(o@pw^T+pb))
        k_gemm<<<dim3(19, 12), 256, 0, stream>>>(hbuf, pw + (size_t)i * 768 * 768,
            pb + (size_t)i * 768, ls1 + (size_t)i * 768, nullptr, xF, T_TOK, 768, 768, 2);
        // LN2
        k_ln<<<T_TOK, 256, 0, stream>>>(xF, n2w + (size_t)i * 768, n2b + (size_t)i * 768, hbuf);
        // fc1 + gelu -> bufA (bf16)
        k_gemm<<<dim3(19, 48), 256, 0, stream>>>(hbuf, f1w + (size_t)i * 3072 * 768,
            f1b + (size_t)i * 3072, nullptr, bufA, nullptr, T_TOK, 3072, 768, 1);
        // fc2 + residual
        k_gemm<<<dim3(19, 12), 256, 0, stream>>>(bufA, f2w + (size_t)i * 768 * 3072,
            f2b_ + (size_t)i * 768, ls2 + (size_t)i * 768, nullptr, xF, T_TOK, 768, 3072, 2);

        // snapshot local_x
        if (i == 2 || i == 4 || i == 8 || i == 10)
            k_cast<<<(int)((TC + 255) / 256), 256, 0, stream>>>(xF, lxB, (int)TC);

        if (i == 2 || i == 5 || i == 8 || i == 11) {
            k_output<<<1152, 256, 0, stream>>>(xF, lxB, fnw, fnb, out_b + (size_t)outIdx * OUT_PER);
            if (i == 11)
                k_cam<<<1, 256, 0, stream>>>(xF, lxB, out_b + 4ull * OUT_PER);
            outIdx++;
        }
    }
}